// Round 9
// baseline (359.304 us; speedup 1.0000x reference)
//
#include <hip/hip_runtime.h>

// B=1024, N=256, F=63, D=64. Only node-0 readout matters:
//   out = (x[:,0] + y[:,0]) @ wf + bf
// v9 = v8 (MFMA formulation) with bandwidth-grade staging:
//  - vec staged as FLAT float4 reads (1KB/instr coalesced, 4-deep MLP) with
//    bf16 LDS scatter-transpose into s_vecT[f][k] (replaces per-lane scalar
//    f32 transpose reads -- the dominant 66MB stream now runs at stream BW).
//  - stage-1 done by waves 0,1 only (one M-tile each, all 4 N-tiles) so each
//    adj neighbor row is fetched exactly once (v8 fetched each twice).
//  - W1 pre-packed to MFMA-frag bf16 in ws by K0 (L2-hot). C/D layout m89.

#define NB 1024
#define NN 256
#define FD 63
#define DM 64
#define MAXP 32
#define VT 264   // s_vecT row stride (shorts): 528B, 16B-aligned
#define W72 72   // s_aggb row stride (shorts): 144B, 16B-aligned
#define NF4 4032 // float4s per batch of vec = 256*63/4

using short8 = __attribute__((ext_vector_type(8))) short;
using f32x4  = __attribute__((ext_vector_type(4))) float;

__device__ __forceinline__ short f2bf(float f) {
    unsigned u = __builtin_bit_cast(unsigned, f);
    return (short)((u + 0x7FFFu + ((u >> 16) & 1u)) >> 16);   // RNE
}

// K0: pack W1rel/W1root into MFMA B-fragment order (bf16), k=63 slot zeroed.
__global__ void k0_w1frag(const float* __restrict__ w1_rel,
                          const float* __restrict__ w1_root,
                          short8* __restrict__ outR,
                          short8* __restrict__ outO)
{
    const int fi = blockIdx.x * blockDim.x + threadIdx.x;   // 0..511
    if (fi >= 512) return;
    const int lane = fi & 63, ksn = fi >> 6;
    const int ks = ksn & 1, nt = ksn >> 1;
    const int n  = (lane & 15) + 16 * nt;
    const int kb = ks * 32 + (lane >> 4) * 8;
    short8 r, o;
    #pragma unroll
    for (int u = 0; u < 8; ++u) {
        const int k = kb + u;
        const bool ok = (k < FD);
        r[u] = ok ? f2bf(w1_rel[k * DM + n])  : (short)0;
        o[u] = ok ? f2bf(w1_root[k * DM + n]) : (short)0;
    }
    outR[fi] = r;
    outO[fi] = o;
}

__launch_bounds__(256, 3)
__global__ void gnn_node0_mfma(const float* __restrict__ adj,
                               const float* __restrict__ vec,
                               const float* __restrict__ b1,
                               const float* __restrict__ w2_rel,
                               const float* __restrict__ w2_root,
                               const float* __restrict__ b2,
                               const float* __restrict__ wf,
                               const float* __restrict__ bf,
                               const short8* __restrict__ w1fR,
                               const short8* __restrict__ w1fO,
                               float* __restrict__ out)
{
    __shared__ __align__(16) short s_vecT[DM * VT];      // vec^T [f][k] bf16, 33.8 KB
    __shared__ __align__(16) short s_aggb[MAXP * W72];   // Agg bf16, 4.6 KB
    __shared__ float s_accp[4][DM];
    __shared__ float s_pA[4][DM];
    __shared__ float s_rA[DM], s_rB[DM], s_r[DM];
    __shared__ float s_a0[MAXP];
    __shared__ int   s_nbr[MAXP];
    __shared__ int   s_cnt, s_p0;

    const int b    = blockIdx.x;
    const int t    = threadIdx.x;
    const int lane = t & 63;
    const int q    = t >> 6;
    const int lr   = lane & 15;        // row/col within 16-tile
    const int lg   = lane >> 4;        // k-group
    const float* adj_b = adj + (size_t)b * NN * NN;
    const float* vec_b = vec + (size_t)b * NN * FD;

    if (t == 0) { s_cnt = 0; s_p0 = 0; }
    if (t < MAXP) { s_a0[t] = 0.f; s_nbr[t] = 0; }
    __syncthreads();                                          // B0

    // ---- node-0 neighbor compaction (unordered; sums commute)
    {
        float a = adj_b[t];
        if (a != 0.f) {
            int idx = atomicAdd(&s_cnt, 1);
            if (idx < MAXP) { s_nbr[idx] = t; s_a0[idx] = a; if (t == 0) s_p0 = idx; }
        }
    }
    __syncthreads();                                          // B1

    // ---- A-prefetch (waves 0,1 only -> each adj row fetched exactly once):
    // wave q owns M-tile rows lr+16q; 16 independent float4 loads per lane.
    f32x4 araw[16];
    if (q < 2) {
        const int jm = s_nbr[lr + 16 * q];      // empty slots -> row 0 (a0=0 masks)
        const float* rp = adj_b + (size_t)jm * NN + lg * 8;
        #pragma unroll
        for (int ks = 0; ks < 8; ++ks) {
            araw[2 * ks]     = *reinterpret_cast<const f32x4*>(rp + ks * 32);
            araw[2 * ks + 1] = *reinterpret_cast<const f32x4*>(rp + ks * 32 + 4);
        }
    }

    // ---- vec staging: flat float4 stream (coalesced 1KB/instr, 4-deep MLP)
    // + bf16 scatter-transpose into s_vecT[f][k].
    {
        const f32x4* vf4 = reinterpret_cast<const f32x4*>(vec_b);
        #pragma unroll
        for (int g = 0; g < 4; ++g) {
            const int base = t + g * 1024;
            f32x4 v0 = {0,0,0,0}, v1 = {0,0,0,0}, v2 = {0,0,0,0}, v3 = {0,0,0,0};
            const bool o0 = base            < NF4;
            const bool o1 = base + 256      < NF4;
            const bool o2 = base + 512      < NF4;
            const bool o3 = base + 768      < NF4;
            if (o0) v0 = vf4[base];
            if (o1) v1 = vf4[base + 256];
            if (o2) v2 = vf4[base + 512];
            if (o3) v3 = vf4[base + 768];
            #pragma unroll
            for (int u = 0; u < 4; ++u) {
                const int ii = base + u * 256;
                if (ii >= NF4) break;
                const f32x4 v = (u == 0) ? v0 : (u == 1) ? v1 : (u == 2) ? v2 : v3;
                const int ee = ii * 4;              // element = k*63 + f
                int k = ee / 63;                    // compiler magic-mul
                int f = ee - k * 63;
                #pragma unroll
                for (int w = 0; w < 4; ++w) {
                    s_vecT[f * VT + k] = f2bf(v[w]);
                    if (++f == FD) { f = 0; ++k; }
                }
            }
        }
        for (int i = t; i < NN; i += 256) s_vecT[63 * VT + i] = 0;  // zero f=63 row
    }

    // ---- convert A to bf16 fragments (loads landed under staging)
    short8 afrag[8];
    if (q < 2) {
        #pragma unroll
        for (int ks = 0; ks < 8; ++ks) {
            short8 s;
            #pragma unroll
            for (int u = 0; u < 4; ++u) {
                s[u]     = f2bf(araw[2 * ks][u]);
                s[4 + u] = f2bf(araw[2 * ks + 1][u]);
            }
            afrag[ks] = s;
        }
    }
    __syncthreads();                                          // B2

    const int p0 = s_p0;

    // ---- stage 1: Agg[32][64] = AdjSub @ vec (waves 0,1: M-tile q x 4 N-tiles)
    if (q < 2) {
        f32x4 A0 = {0,0,0,0}, A1 = {0,0,0,0}, A2 = {0,0,0,0}, A3 = {0,0,0,0};
        const short* b0p = &s_vecT[(lr     ) * VT + lg * 8];
        const short* b1p = &s_vecT[(lr + 16) * VT + lg * 8];
        const short* b2p = &s_vecT[(lr + 32) * VT + lg * 8];
        const short* b3p = &s_vecT[(lr + 48) * VT + lg * 8];
        #pragma unroll
        for (int ks = 0; ks < 8; ++ks) {
            const short8 f0 = *reinterpret_cast<const short8*>(b0p + ks * 32);
            const short8 f1 = *reinterpret_cast<const short8*>(b1p + ks * 32);
            const short8 f2 = *reinterpret_cast<const short8*>(b2p + ks * 32);
            const short8 f3 = *reinterpret_cast<const short8*>(b3p + ks * 32);
            A0 = __builtin_amdgcn_mfma_f32_16x16x32_bf16(afrag[ks], f0, A0, 0, 0, 0);
            A1 = __builtin_amdgcn_mfma_f32_16x16x32_bf16(afrag[ks], f1, A1, 0, 0, 0);
            A2 = __builtin_amdgcn_mfma_f32_16x16x32_bf16(afrag[ks], f2, A2, 0, 0, 0);
            A3 = __builtin_amdgcn_mfma_f32_16x16x32_bf16(afrag[ks], f3, A3, 0, 0, 0);
        }
        // C/D layout (m89): col = lane&15, row = (lane>>4)*4 + reg
        #pragma unroll
        for (int r = 0; r < 4; ++r) {
            const int row = lg * 4 + r + 16 * q;
            s_aggb[row * W72 + lr     ] = f2bf(A0[r]);
            s_aggb[row * W72 + lr + 16] = f2bf(A1[r]);
            s_aggb[row * W72 + lr + 32] = f2bf(A2[r]);
            s_aggb[row * W72 + lr + 48] = f2bf(A3[r]);
        }
    }
    __syncthreads();                                          // B3

    // ---- stage 2: X = relu(Agg@W1rel + Vsel@W1root + b1); 4-wave split
    {
        const int mt  = q & 1;
        const int ntb = (q >> 1) * 2;
        f32x4 acc0 = {0,0,0,0};
        f32x4 acc1 = {0,0,0,0};
        const int prow = lr + 16 * mt;                 // this lane's pair slot
        const int jsel = s_nbr[prow];                  // 0 if slot empty
        const short* aggrow = &s_aggb[prow * W72 + lg * 8];
        #pragma unroll
        for (int ks = 0; ks < 2; ++ks) {
            const int ko = ks * 32 + lg * 8;
            const short8 aA = *reinterpret_cast<const short8*>(aggrow + ks * 32);
            short8 aV;
            #pragma unroll
            for (int u = 0; u < 8; ++u)                // Vsel[prow][f] = vecT[f][jsel]
                aV[u] = s_vecT[(ko + u) * VT + jsel];  // f=63 row is zeros
            const short8 vR0 = w1fR[((ntb    ) * 2 + ks) * 64 + lane];
            const short8 vR1 = w1fR[((ntb + 1) * 2 + ks) * 64 + lane];
            const short8 vO0 = w1fO[((ntb    ) * 2 + ks) * 64 + lane];
            const short8 vO1 = w1fO[((ntb + 1) * 2 + ks) * 64 + lane];
            acc0 = __builtin_amdgcn_mfma_f32_16x16x32_bf16(aA, vR0, acc0, 0, 0, 0);
            acc0 = __builtin_amdgcn_mfma_f32_16x16x32_bf16(aV, vO0, acc0, 0, 0, 0);
            acc1 = __builtin_amdgcn_mfma_f32_16x16x32_bf16(aA, vR1, acc1, 0, 0, 0);
            acc1 = __builtin_amdgcn_mfma_f32_16x16x32_bf16(aV, vO1, acc1, 0, 0, 0);
        }
        const int c0 = lr + 16 * ntb, c1 = c0 + 16;
        const float bc0 = b1[c0], bc1 = b1[c1];
        float aY0 = 0.f, aY1 = 0.f;
        #pragma unroll
        for (int r = 0; r < 4; ++r) {
            const int row = lg * 4 + r + 16 * mt;      // pair slot of this C-elem
            const float a0 = s_a0[row];                // 0 for empty slots
            const float x0v = fmaxf(acc0[r] + bc0, 0.f);
            const float x1v = fmaxf(acc1[r] + bc1, 0.f);
            aY0 += a0 * x0v;
            aY1 += a0 * x1v;
            if (row == p0) { s_rB[c0] = x0v; s_rB[c1] = x1v; }  // x[b,0]
        }
        // reduce partial accY across the 4 k-groups (lane bits 4-5)
        aY0 += __shfl_xor(aY0, 16); aY0 += __shfl_xor(aY0, 32);
        aY1 += __shfl_xor(aY1, 16); aY1 += __shfl_xor(aY1, 32);
        if (lg == 0) { s_accp[q][c0] = aY0; s_accp[q][c1] = aY1; }
    }
    __syncthreads();                                          // B4

    // ---- accY = sum over the mt-pair of waves covering this column
    if (q == 0) {
        const int qp = 2 * (lane >> 5);
        s_rA[lane] = s_accp[qp][lane] + s_accp[qp + 1][lane];
    }
    __syncthreads();                                          // B5

    // ---- layer 2 row 0: y0 = relu(accY@w2_rel + x0@w2_root + b2), 4-wave split
    {
        float p = 0.f;
        const int f0 = q * 16;
        #pragma unroll
        for (int ff2 = 0; ff2 < 16; ++ff2) {
            const int ff = f0 + ff2;
            p += s_rA[ff] * w2_rel[ff * DM + lane]
               + s_rB[ff] * w2_root[ff * DM + lane];
        }
        s_pA[q][lane] = p;
    }
    __syncthreads();                                          // B6
    if (t < DM) {
        const float y = fmaxf(s_pA[0][t] + s_pA[1][t] + s_pA[2][t] + s_pA[3][t] + b2[t], 0.f);
        s_r[t] = s_rB[t] + y;                          // x0 + y0
    }
    __syncthreads();                                          // B7
    if (t < 2) {
        float acc = bf[t];
        #pragma unroll
        for (int d = 0; d < DM; ++d) acc += s_r[d] * wf[d * 2 + t];
        out[b * 2 + t] = acc;
    }
}

extern "C" void kernel_launch(void* const* d_in, const int* in_sizes, int n_in,
                              void* d_out, int out_size, void* d_ws, size_t ws_size,
                              hipStream_t stream) {
    const float* adj     = (const float*)d_in[0];
    const float* vec     = (const float*)d_in[1];
    const float* w1_rel  = (const float*)d_in[2];
    const float* w1_root = (const float*)d_in[3];
    const float* b1      = (const float*)d_in[4];
    const float* w2_rel  = (const float*)d_in[5];
    const float* w2_root = (const float*)d_in[6];
    const float* b2      = (const float*)d_in[7];
    const float* wf      = (const float*)d_in[8];
    const float* bf      = (const float*)d_in[9];
    float* out = (float*)d_out;

    short8* wsR = (short8*)d_ws;            // 512 frags (8 KB)
    short8* wsO = wsR + 512;                // 8 KB

    k0_w1frag<<<2, 256, 0, stream>>>(w1_rel, w1_root, wsR, wsO);
    gnn_node0_mfma<<<NB, 256, 0, stream>>>(adj, vec, b1, w2_rel, w2_root,
                                           b2, wf, bf, wsR, wsO, out);
}